// Round 19
// baseline (542.197 us; speedup 1.0000x reference)
//
#include <hip/hip_runtime.h>
#include <hip/hip_bf16.h>
#include <cstdint>
#include <cstddef>

constexpr int N_  = 20000;
constexpr int E_  = 320000;
constexpr int DIM_ = 128;
constexpr int L_  = 4;
constexpr int MP_ = 20032;   // M padded

typedef short bf16x8 __attribute__((ext_vector_type(8)));
typedef float f32x4  __attribute__((ext_vector_type(4)));

__device__ __forceinline__ float gelu_f(float x) {
  float x3 = x * x * x;
  float z = 0.7978845608028654f * (x + 0.044715f * x3);
  float t = 1.f - 2.f / (__expf(2.f * z) + 1.f);   // tanh via fast exp
  return 0.5f * x * (1.0f + t);
}

__device__ __forceinline__ unsigned short f2bf(float x) {  // RNE
  unsigned u = __float_as_uint(x);
  u += 0x7fff + ((u >> 16) & 1);
  return (unsigned short)(u >> 16);
}
__device__ __forceinline__ float bf2f(unsigned short s) {
  return __uint_as_float((unsigned)s << 16);
}
__device__ __forceinline__ void splitf(float x, unsigned short& h, unsigned short& l) {
  h = f2bf(x);
  l = f2bf(x - bf2f(h));
}

// cls_ws layout offsets (floats)
constexpr int CW1_OFF  = 0;
constexpr int CW2_OFF  = 32768;
constexpr int CLSW_OFF = 65536;
constexpr int CB1_OFF  = 66816;
constexpr int CB2_OFF  = 67072;
constexpr int CLSB_OFF = 67200;
constexpr int CLNW_OFF = 67216;
constexpr int CLNB_OFF = 67344;
constexpr int CLS_TOT  = 67472;

// ---------------------------------------------------------------------------
// MFMA GEMM v5: fragment-major LDS staging, register-prefetched B staging.
// BSPLIT: B weights have a lo-plane (2 MFMAs/tile) or single bf16 (1 MFMA).
// ASPLIT: A has a lo-plane. RW = row-frags/wave. WB: 0 none,1 hi/lo,2 bf16.
// EPI: 0 none, 1 gelu, 2 +res. QPACK: q bf16 pre-scaled (Clo) + kv (Chi).
// ---------------------------------------------------------------------------
template <int K, int NC, int EPI, bool WF32, int WB, bool QPACK, bool ASPLIT,
          int RW, bool BSPLIT>
__global__ __launch_bounds__(128, 4) void mgemm3_k(
    const unsigned short* __restrict__ Ahi, const unsigned short* __restrict__ Alo,
    const unsigned short* __restrict__ Bthi, const unsigned short* __restrict__ Btlo,
    const float* __restrict__ bias, const float* __restrict__ res,
    float* __restrict__ Cf, float* __restrict__ Cf2,
    unsigned short* __restrict__ Chi, unsigned short* __restrict__ Clo,
    int M)
{
  constexpr int NCY = NC / 64;
  constexpr int BR  = RW * 32;
  constexpr int RPB = (RW == 2) ? 40 : 79;
  __shared__ unsigned short BsH[8 * 512];
  __shared__ unsigned short BsL[BSPLIT ? 8 * 512 : 8];

  const int bid = blockIdx.x;
  const int g   = bid & 7;
  const int s   = bid >> 3;
  const int lr  = s / NCY;
  const int cc  = s - lr * NCY;
  const int rb  = g * RPB + lr;
  if (rb * BR >= M) return;

  const int tid  = threadIdx.x;
  const int wave = tid >> 6;
  const int lane = tid & 63;
  const int l15  = lane & 15;
  const int kq8  = (lane >> 4) * 8;
  const int r0   = rb * BR + wave * (RW * 16);
  const int c0   = cc * 64;

  const int brow  = tid & 63;
  const int bhalf = tid >> 6;
  const int sbase = ((brow >> 4) * 2 + bhalf) * 512 + (brow & 15) * 8;
  const unsigned short* bh_src = Bthi + (size_t)(c0 + brow) * K + bhalf * 32;
  const unsigned short* bl_src = BSPLIT ? (Btlo + (size_t)(c0 + brow) * K + bhalf * 32)
                                        : bh_src;

  f32x4 acc[RW][4];
#pragma unroll
  for (int rw = 0; rw < RW; ++rw)
#pragma unroll
    for (int ct = 0; ct < 4; ++ct) acc[rw][ct] = (f32x4){0.f, 0.f, 0.f, 0.f};

  const unsigned short* arh[2];
  const unsigned short* arl[2];
  arh[0] = Ahi + (size_t)(r0 + l15) * K + kq8;
  arh[1] = (RW == 2) ? (Ahi + (size_t)(r0 + 16 + l15) * K + kq8) : arh[0];
  arl[0] = ASPLIT ? (Alo + (size_t)(r0 + l15) * K + kq8) : arh[0];
  arl[1] = (ASPLIT && RW == 2) ? (Alo + (size_t)(r0 + 16 + l15) * K + kq8) : arl[0];

  constexpr int NCH = K / 64;
  bf16x8 rh0[4], rl0[4], rh1[4], rl1[4];
#pragma unroll
  for (int st = 0; st < 4; ++st) {
    rh0[st] = *(const bf16x8*)(bh_src + st * 8);
    if constexpr (BSPLIT) rl0[st] = *(const bf16x8*)(bl_src + st * 8);
  }

#pragma unroll
  for (int c = 0; c < NCH; ++c) {
    const int ck = c * 64;
    if (c > 0) __syncthreads();
#pragma unroll
    for (int st = 0; st < 4; ++st) {
      if (c & 1) {
        *(bf16x8*)&BsH[sbase + st * 128] = rh1[st];
        if constexpr (BSPLIT) *(bf16x8*)&BsL[sbase + st * 128] = rl1[st];
      } else {
        *(bf16x8*)&BsH[sbase + st * 128] = rh0[st];
        if constexpr (BSPLIT) *(bf16x8*)&BsL[sbase + st * 128] = rl0[st];
      }
    }
    if (c + 1 < NCH) {
      const int ck2 = (c + 1) * 64;
#pragma unroll
      for (int st = 0; st < 4; ++st) {
        if (c & 1) {
          rh0[st] = *(const bf16x8*)(bh_src + ck2 + st * 8);
          if constexpr (BSPLIT) rl0[st] = *(const bf16x8*)(bl_src + ck2 + st * 8);
        } else {
          rh1[st] = *(const bf16x8*)(bh_src + ck2 + st * 8);
          if constexpr (BSPLIT) rl1[st] = *(const bf16x8*)(bl_src + ck2 + st * 8);
        }
      }
    }
    __syncthreads();
#pragma unroll
    for (int k0 = 0; k0 < 2; ++k0) {
      bf16x8 ah[RW], al[RW];
#pragma unroll
      for (int rw = 0; rw < RW; ++rw) {
        ah[rw] = *(const bf16x8*)(arh[rw] + ck + k0 * 32);
        if (ASPLIT) al[rw] = *(const bf16x8*)(arl[rw] + ck + k0 * 32);
      }
#pragma unroll
      for (int ct = 0; ct < 4; ++ct) {
        const int fb = (ct * 2 + k0) * 512 + lane * 8;
        bf16x8 bh = *(const bf16x8*)&BsH[fb];
#pragma unroll
        for (int rw = 0; rw < RW; ++rw) {
          acc[rw][ct] = __builtin_amdgcn_mfma_f32_16x16x32_bf16(ah[rw], bh, acc[rw][ct], 0, 0, 0);
          if constexpr (BSPLIT) {
            bf16x8 bl = *(const bf16x8*)&BsL[fb];
            acc[rw][ct] = __builtin_amdgcn_mfma_f32_16x16x32_bf16(ah[rw], bl, acc[rw][ct], 0, 0, 0);
          }
          if (ASPLIT)
            acc[rw][ct] = __builtin_amdgcn_mfma_f32_16x16x32_bf16(al[rw], bh, acc[rw][ct], 0, 0, 0);
        }
      }
    }
  }

  const int ccol  = lane & 15;
  const int crow0 = (lane >> 4) * 4;
#pragma unroll
  for (int rw = 0; rw < RW; ++rw) {
#pragma unroll
    for (int ct = 0; ct < 4; ++ct) {
      int gc = c0 + ct * 16 + ccol;
      float bb = bias[gc];
#pragma unroll
      for (int r = 0; r < 4; ++r) {
        int gr = r0 + rw * 16 + crow0 + r;
        if (gr >= M) continue;
        float o = acc[rw][ct][r] + bb;
        if (EPI == 1) o = gelu_f(o);
        if (EPI == 2) o += res[(size_t)gr * NC + gc];
        if (QPACK) {
          if (c0 < 128) Clo[(size_t)gr * 128 + gc] = f2bf(o * 0.17677669529663687f);
          else          Chi[(size_t)gr * 256 + gc - 128] = f2bf(o);
        } else {
          if (WF32) {
            Cf[(size_t)gr * NC + gc] = o;
            if (Cf2) Cf2[(size_t)gr * NC + gc] = o;
          }
          if (WB == 1) {
            unsigned short hh, ll;
            splitf(o, hh, ll);
            Chi[(size_t)gr * NC + gc] = hh;
            Clo[(size_t)gr * NC + gc] = ll;
          }
          if (WB == 2) Chi[(size_t)gr * NC + gc] = f2bf(o);
        }
      }
    }
  }
}

// ---------------------------------------------------------------------------
// Fused O-projection + residual + LayerNorm. 1-wave blocks (16 rows), no LDS,
// grid 1250 for latency hiding. B single bf16 plane.
// ---------------------------------------------------------------------------
__global__ __launch_bounds__(64, 8) void ogemm_ln_k(
    const unsigned short* __restrict__ A,
    const unsigned short* __restrict__ Bt,
    const float* __restrict__ bias, const float* __restrict__ resid,
    const float* __restrict__ lnw, const float* __restrict__ lnb,
    float* __restrict__ lnF, unsigned short* __restrict__ lnB, int M)
{
  const int lane = threadIdx.x & 63;
  const int l15  = lane & 15;
  const int kq8  = (lane >> 4) * 8;
  const int r0   = blockIdx.x * 16;
  if (r0 >= M) return;

  f32x4 acc[8];
#pragma unroll
  for (int ct = 0; ct < 8; ++ct) acc[ct] = (f32x4){0.f, 0.f, 0.f, 0.f};

  const unsigned short* ar  = A + (size_t)(r0 + l15) * 128 + kq8;
  const unsigned short* bth = Bt + (size_t)l15 * 128 + kq8;

#pragma unroll
  for (int k0 = 0; k0 < 128; k0 += 32) {
    bf16x8 ah = *(const bf16x8*)(ar + k0);
#pragma unroll
    for (int ct = 0; ct < 8; ++ct) {
      bf16x8 bh = *(const bf16x8*)(bth + ct * 16 * 128 + k0);
      acc[ct] = __builtin_amdgcn_mfma_f32_16x16x32_bf16(ah, bh, acc[ct], 0, 0, 0);
    }
  }

  const int ccol  = lane & 15;
  const int crow0 = (lane >> 4) * 4;

#pragma unroll
  for (int ct = 0; ct < 8; ++ct) {
    int gc = ct * 16 + ccol;
    float bb = bias[gc];
#pragma unroll
    for (int r = 0; r < 4; ++r) {
      int gr = r0 + crow0 + r;
      acc[ct][r] += bb + resid[(size_t)gr * 128 + gc];
    }
  }

  float mu[4];
#pragma unroll
  for (int r = 0; r < 4; ++r) {
    float s = 0.f;
#pragma unroll
    for (int ct = 0; ct < 8; ++ct) s += acc[ct][r];
    s += __shfl_xor(s, 1); s += __shfl_xor(s, 2);
    s += __shfl_xor(s, 4); s += __shfl_xor(s, 8);
    mu[r] = s * (1.f / 128.f);
  }
  float rstd[4];
#pragma unroll
  for (int r = 0; r < 4; ++r) {
    float s = 0.f;
#pragma unroll
    for (int ct = 0; ct < 8; ++ct) { float d = acc[ct][r] - mu[r]; s += d * d; }
    s += __shfl_xor(s, 1); s += __shfl_xor(s, 2);
    s += __shfl_xor(s, 4); s += __shfl_xor(s, 8);
    rstd[r] = rsqrtf(s * (1.f / 128.f) + 1e-5f);
  }

#pragma unroll
  for (int ct = 0; ct < 8; ++ct) {
    int gc = ct * 16 + ccol;
    float ww = lnw[gc], bb = lnb[gc];
#pragma unroll
    for (int r = 0; r < 4; ++r) {
      int gr = r0 + crow0 + r;
      if (gr >= M) continue;
      float o = (acc[ct][r] - mu[r]) * rstd[r] * ww + bb;
      lnF[(size_t)gr * 128 + gc] = o;
      lnB[(size_t)gr * 128 + gc] = f2bf(o);
    }
  }
}

// ---------------------------------------------------------------------------
// prep_k: weight prep (all layer weights single bf16; embed keeps hi/lo) +
// classifier warm-copy + zeroing.
// ---------------------------------------------------------------------------
__global__ __launch_bounds__(256) void prep_k(
    const float* __restrict__ qw, const float* __restrict__ kw,
    const float* __restrict__ vw, const float* __restrict__ ow,
    const float* __restrict__ mw1, const float* __restrict__ mw2,
    const float* __restrict__ emb_w,
    const float* __restrict__ qb, const float* __restrict__ kb,
    const float* __restrict__ vb,
    const float* __restrict__ nf,
    const float* __restrict__ cw1, const float* __restrict__ cw2,
    const float* __restrict__ clsw, const float* __restrict__ cb1,
    const float* __restrict__ cb2, const float* __restrict__ clsb,
    const float* __restrict__ clnw, const float* __restrict__ clnb,
    unsigned short* __restrict__ wqkv_hi,
    unsigned short* __restrict__ wo_hi,
    unsigned short* __restrict__ w1_hi,
    unsigned short* __restrict__ w2_hi,
    unsigned short* __restrict__ we_hi, unsigned short* __restrict__ we_lo,
    float* __restrict__ qkvb,
    unsigned short* __restrict__ nf_hi, unsigned short* __restrict__ nf_lo,
    int* __restrict__ deg, int* __restrict__ cur,
    float* __restrict__ cls_ws)
{
  constexpr int T_qkv = 3 * L_ * 16384;
  constexpr int T_o   = T_qkv + L_ * 16384;
  constexpr int T_w1  = T_o + L_ * 65536;
  constexpr int T_w2  = T_w1 + L_ * 65536;
  constexpr int T_we  = T_w2 + 8192;
  constexpr int T_b   = T_we + L_ * 384;
  constexpr int T_nf  = T_b + N_ * 64;
  constexpr int T_z   = T_nf + 2 * N_;
  constexpr int T_cls = T_z + CLS_TOT;

  unsigned short hh, ll;
  for (int i = blockIdx.x * 256 + threadIdx.x; i < T_cls; i += gridDim.x * 256) {
    if (i < T_qkv) {
      int which = i / (L_ * 16384);
      int r = i - which * (L_ * 16384);
      int l = r >> 14, rr = r & 16383;
      int k = rr >> 7, c = rr & 127;
      const float* src = (which == 0) ? qw : (which == 1) ? kw : vw;
      size_t op = (size_t)l * 49152 + (size_t)(which * 128 + c) * 128 + k;
      wqkv_hi[op] = f2bf(src[r]);
    } else if (i < T_o) {
      int r = i - T_qkv;
      int l = r >> 14, rr = r & 16383;
      int k = rr >> 7, c = rr & 127;
      size_t op = (size_t)l * 16384 + (size_t)c * 128 + k;
      wo_hi[op] = f2bf(ow[r]);
    } else if (i < T_w1) {
      int r = i - T_o;
      int l = r >> 16, rr = r & 65535;
      int k = rr >> 9, c = rr & 511;
      size_t op = (size_t)l * 65536 + (size_t)c * 128 + k;
      w1_hi[op] = f2bf(mw1[r]);
    } else if (i < T_w2) {
      int r = i - T_w1;
      int l = r >> 16, rr = r & 65535;
      int k = rr >> 7, c = rr & 127;
      size_t op = (size_t)l * 65536 + (size_t)c * 512 + k;
      w2_hi[op] = f2bf(mw2[r]);
    } else if (i < T_we) {
      int r = i - T_w2;
      int k = r >> 7, c = r & 127;
      splitf(emb_w[r], hh, ll);
      size_t op = (size_t)c * 64 + k;
      we_hi[op] = hh; we_lo[op] = ll;
    } else if (i < T_b) {
      int r = i - T_we;
      int l = r / 384, c = r - l * 384;
      float x = (c < 128) ? qb[l * 128 + c]
              : (c < 256) ? kb[l * 128 + c - 128]
                          : vb[l * 128 + c - 256];
      qkvb[r] = x;
    } else if (i < T_nf) {
      int r = i - T_b;
      splitf(nf[r], hh, ll);
      nf_hi[r] = hh; nf_lo[r] = ll;
    } else if (i < T_z) {
      int r = i - T_nf;
      if (r < N_) deg[r] = 0;
      else cur[r - N_] = 0;
    } else {
      int j = i - T_z;
      float v;
      if (j < CW2_OFF)       v = cw1[j];
      else if (j < CLSW_OFF) v = cw2[j - CW2_OFF];
      else if (j < CB1_OFF)  v = clsw[j - CLSW_OFF];
      else if (j < CB2_OFF)  v = cb1[j - CB1_OFF];
      else if (j < CLSB_OFF) v = cb2[j - CB2_OFF];
      else if (j < CLNW_OFF) v = (j - CLSB_OFF < 10) ? clsb[j - CLSB_OFF] : 0.f;
      else if (j < CLNB_OFF) v = clnw[j - CLNW_OFF];
      else                   v = clnb[j - CLNB_OFF];
      cls_ws[j] = v;
    }
  }
}

// ---------------------------------------------------------------------------
// CSR build
// ---------------------------------------------------------------------------
__global__ __launch_bounds__(256) void deg_k(const int* __restrict__ dst, int* __restrict__ deg, int E) {
  int e = blockIdx.x * blockDim.x + threadIdx.x;
  if (e < E) atomicAdd(&deg[dst[e]], 1);
}

__global__ __launch_bounds__(1024) void scan_k(const int* __restrict__ deg, int* __restrict__ offs, int n) {
  __shared__ int part[1024];
  int tid = threadIdx.x;
  const int chunk = (n + 1023) / 1024;
  int base = tid * chunk;
  int s = 0;
  for (int j = 0; j < chunk; ++j) { int idx = base + j; if (idx < n) s += deg[idx]; }
  part[tid] = s;
  __syncthreads();
  int own = s;
  for (int off = 1; off < 1024; off <<= 1) {
    int t = (tid >= off) ? part[tid - off] : 0;
    __syncthreads();
    part[tid] += t;
    __syncthreads();
  }
  int run = part[tid] - own;
  for (int j = 0; j < chunk; ++j) {
    int idx = base + j;
    if (idx <= n) offs[idx] = run;
    if (idx < n) run += deg[idx];
  }
}

__global__ __launch_bounds__(256) void fill_k(
    const int* __restrict__ src, const int* __restrict__ dst,
    const int* __restrict__ offs, int* __restrict__ cur,
    int* __restrict__ csrc, int E)
{
  int e = blockIdx.x * blockDim.x + threadIdx.x;
  if (e < E) {
    int d = dst[e];
    int p = atomicAdd(&cur[d], 1);
    csrc[offs[d] + p] = src[e];
  }
}

// ---------------------------------------------------------------------------
// Fused attention v3: wave per node, 16-edge chunks x 4 heads, early V-issue.
// ---------------------------------------------------------------------------
__global__ __launch_bounds__(256) void agg_k(
    const unsigned short* __restrict__ qbf, const unsigned short* __restrict__ kvbf,
    const int* __restrict__ offs, const int* __restrict__ csrc,
    unsigned short* __restrict__ agg, int M)
{
  int nb = blockIdx.x;
  int bid = (nb & 7) * 625 + (nb >> 3);
  int n = bid * 4 + (int)(threadIdx.x >> 6);
  int lane = threadIdx.x & 63;
  if (n >= M) return;
  const int e0 = offs[n], e1 = offs[n + 1];
  const int col2 = lane * 2;
  if (e0 == e1) {
    *(unsigned*)&agg[(size_t)n * 128 + col2] = 0;
    return;
  }
  const int eloc = lane & 15;
  const int hgrp = lane & 48;

  const unsigned short* qr = qbf + (size_t)n * 128 + (lane >> 4) * 32;
  float qf[32];
#pragma unroll
  for (int i = 0; i < 4; ++i) {
    uint4 t = *(const uint4*)(qr + i * 8);
    unsigned u0 = t.x, u1 = t.y, u2 = t.z, u3 = t.w;
    qf[i * 8 + 0] = __uint_as_float(u0 << 16);
    qf[i * 8 + 1] = __uint_as_float(u0 & 0xffff0000u);
    qf[i * 8 + 2] = __uint_as_float(u1 << 16);
    qf[i * 8 + 3] = __uint_as_float(u1 & 0xffff0000u);
    qf[i * 8 + 4] = __uint_as_float(u2 << 16);
    qf[i * 8 + 5] = __uint_as_float(u2 & 0xffff0000u);
    qf[i * 8 + 6] = __uint_as_float(u3 << 16);
    qf[i * 8 + 7] = __uint_as_float(u3 & 0xffff0000u);
  }

  float denp = 0.f, acc0 = 0.f, acc1 = 0.f;
  for (int c = e0; c < e1; c += 16) {
    int e = c + eloc;
    bool val = e < e1;
    int sv = csrc[val ? e : e1 - 1];

    unsigned vv[16];
#pragma unroll
    for (int i = 0; i < 16; ++i) {
      int sb = __shfl(sv, hgrp + i);
      vv[i] = *(const unsigned*)(kvbf + (size_t)sb * 256 + 128 + col2);
    }

    const unsigned short* kr = kvbf + (size_t)sv * 256 + (lane >> 4) * 32;
    float dot = 0.f;
#pragma unroll
    for (int i = 0; i < 4; ++i) {
      uint4 t = *(const uint4*)(kr + i * 8);
      unsigned u0 = t.x, u1 = t.y, u2 = t.z, u3 = t.w;
      dot = fmaf(qf[i * 8 + 0], __uint_as_float(u0 << 16), dot);
      dot = fmaf(qf[i * 8 + 1], __uint_as_float(u0 & 0xffff0000u), dot);
      dot = fmaf(qf[i * 8 + 2], __uint_as_float(u1 << 16), dot);
      dot = fmaf(qf[i * 8 + 3], __uint_as_float(u1 & 0xffff0000u), dot);
      dot = fmaf(qf[i * 8 + 4], __uint_as_float(u2 << 16), dot);
      dot = fmaf(qf[i * 8 + 5], __uint_as_float(u2 & 0xffff0000u), dot);
      dot = fmaf(qf[i * 8 + 6], __uint_as_float(u3 << 16), dot);
      dot = fmaf(qf[i * 8 + 7], __uint_as_float(u3 & 0xffff0000u), dot);
    }
    float w = val ? __expf(dot) : 0.f;
    denp += w;

#pragma unroll
    for (int i = 0; i < 16; ++i) {
      float wi = __shfl(w, hgrp + i);
      acc0 = fmaf(wi, __uint_as_float(vv[i] << 16), acc0);
      acc1 = fmaf(wi, __uint_as_float(vv[i] & 0xffff0000u), acc1);
    }
  }
  float den = denp;
  den += __shfl_xor(den, 1);
  den += __shfl_xor(den, 2);
  den += __shfl_xor(den, 4);
  den += __shfl_xor(den, 8);
  float r = 1.f / den;
  unsigned o0 = f2bf(acc0 * r);
  unsigned o1 = f2bf(acc1 * r);
  *(unsigned*)&agg[(size_t)n * 128 + col2] = o0 | (o1 << 16);
}

// ---------------------------------------------------------------------------
// Column sum stage 1
// ---------------------------------------------------------------------------
__global__ __launch_bounds__(256) void colsum1_k(
    const float* __restrict__ h, float* __restrict__ partial, int M)
{
  __shared__ float sd[8][128];
  int tid = threadIdx.x;
  int cq = (tid & 31) * 4;
  int rg = tid >> 5;
  float4 s = make_float4(0.f, 0.f, 0.f, 0.f);
  for (int r = blockIdx.x * 8 + rg; r < M; r += gridDim.x * 8) {
    float4 v = *(const float4*)(h + (size_t)r * 128 + cq);
    s.x += v.x; s.y += v.y; s.z += v.z; s.w += v.w;
  }
  *(float4*)&sd[rg][cq] = s;
  __syncthreads();
  if (tid < 32) {
    int c4 = tid * 4;
    float4 a = *(float4*)&sd[0][c4];
#pragma unroll
    for (int g2 = 1; g2 < 8; ++g2) {
      float4 b = *(float4*)&sd[g2][c4];
      a.x += b.x; a.y += b.y; a.z += b.z; a.w += b.w;
    }
    *(float4*)&partial[(size_t)blockIdx.x * 128 + c4] = a;
  }
}

// ---------------------------------------------------------------------------
// classifier: 1024 threads, LDS-split dots, L3-warm cls_ws copy.
// ---------------------------------------------------------------------------
__global__ __launch_bounds__(1024) void classifier_k(
    const float* __restrict__ partial, int P,
    const float* __restrict__ cls,
    float* __restrict__ out_logits, float* __restrict__ out_g, float invN)
{
  __shared__ float scratch[1024];
  __shared__ float z[128], h1b[256], z2[128];
  const int tid = threadIdx.x;

  {
    int col = tid & 127, ch = tid >> 7;
    float s = 0.f;
    for (int i = ch; i < P; i += 8) s += partial[(size_t)i * 128 + col];
    scratch[tid] = s;
  }
  __syncthreads();
  if (tid < 128) {
    float s = 0.f;
#pragma unroll
    for (int j = 0; j < 8; ++j) s += scratch[tid + j * 128];
    float gg = s * invN;
    out_g[tid] = gg;
    z[tid] = gg;
  }
  __syncthreads();

  if (tid < 64) {
    float a = z[tid], b2 = z[tid + 64];
    float s = a + b2;
#pragma unroll
    for (int d = 1; d < 64; d <<= 1) s += __shfl_xor(s, d);
    float mean = s * (1.f / 128.f);
    float ea = a - mean, eb = b2 - mean;
    float sq = ea * ea + eb * eb;
#pragma unroll
    for (int d = 1; d < 64; d <<= 1) sq += __shfl_xor(sq, d);
    float rstd = rsqrtf(sq * (1.f / 128.f) + 1e-5f);
    z[tid]      = ea * rstd * cls[CLNW_OFF + tid] + cls[CLNB_OFF + tid];
    z[tid + 64] = eb * rstd * cls[CLNW_OFF + tid + 64] + cls[CLNB_OFF + tid + 64];
  }
  __syncthreads();

  {
    int o = tid & 255, ch = tid >> 8;
    float s = 0.f;
#pragma unroll
    for (int f = 0; f < 32; ++f)
      s = fmaf(z[ch * 32 + f], cls[CW1_OFF + (ch * 32 + f) * 256 + o], s);
    scratch[tid] = s;
  }
  __syncthreads();
  if (tid < 256) {
    float s = cls[CB1_OFF + tid];
#pragma unroll
    for (int j = 0; j < 4; ++j) s += scratch[tid + j * 256];
    h1b[tid] = gelu_f(s);
  }
  __syncthreads();

  {
    int o = tid & 127, ch = tid >> 7;
    float s = 0.f;
#pragma unroll
    for (int f = 0; f < 32; ++f)
      s = fmaf(h1b[ch * 32 + f], cls[CW2_OFF + (ch * 32 + f) * 128 + o], s);
    scratch[tid] = s;
  }
  __syncthreads();
  if (tid < 128) {
    float s = cls[CB2_OFF + tid];
#pragma unroll
    for (int j = 0; j < 8; ++j) s += scratch[tid + j * 128];
    z2[tid] = s;
  }
  __syncthreads();

  {
    int wv = tid >> 6, ln = tid & 63;
    if (wv < 10) {
      float s = z2[ln] * cls[CLSW_OFF + ln * 10 + wv]
              + z2[ln + 64] * cls[CLSW_OFF + (ln + 64) * 10 + wv];
#pragma unroll
      for (int d = 1; d < 64; d <<= 1) s += __shfl_xor(s, d);
      if (ln == 0) out_logits[wv] = s + cls[CLSB_OFF + wv];
    }
  }
}

// ---------------------------------------------------------------------------
extern "C" void kernel_launch(void* const* d_in, const int* in_sizes, int n_in,
                              void* d_out, int out_size, void* d_ws, size_t ws_size,
                              hipStream_t stream) {
  const float* node_features = (const float*)d_in[0];
  const int*   ei            = (const int*)d_in[1];
  const float* emb_w = (const float*)d_in[3];
  const float* emb_b = (const float*)d_in[4];
  const float* qw  = (const float*)d_in[7];  const float* qb  = (const float*)d_in[8];
  const float* kw  = (const float*)d_in[9];  const float* kb  = (const float*)d_in[10];
  const float* vw  = (const float*)d_in[11]; const float* vb  = (const float*)d_in[12];
  const float* ow  = (const float*)d_in[13]; const float* ob  = (const float*)d_in[14];
  const float* lnw = (const float*)d_in[15]; const float* lnb = (const float*)d_in[16];
  const float* mw1 = (const float*)d_in[17]; const float* mb1 = (const float*)d_in[18];
  const float* mw2 = (const float*)d_in[19]; const float* mb2 = (const float*)d_in[20];
  const float* clnw = (const float*)d_in[21]; const float* clnb = (const float*)d_in[22];
  const float* cw1 = (const float*)d_in[23]; const float* cb1 = (const float*)d_in[24];
  const float* cw2 = (const float*)d_in[25]; const float* cb2 = (const float*)d_in[26];
  const float* clsw = (const float*)d_in[27]; const float* clsb = (const float*)d_in[28];

  float* out = (float*)d_out;
  float* out_h = out + 10;
  float* out_g = out + 10 + (size_t)N_ * DIM_;

  char* p = (char*)d_ws;
  auto alloc = [&](size_t bytes) { char* r = p; p += (bytes + 255) & ~(size_t)255; return r; };

  float* h    = (float*)alloc((size_t)MP_ * 128 * 4);
  float* tmp  = (float*)alloc((size_t)MP_ * 128 * 4);
  unsigned short* qbf  = (unsigned short*)alloc((size_t)MP_ * 128 * 2);
  unsigned short* kvbf = (unsigned short*)alloc((size_t)MP_ * 256 * 2);
  unsigned short* h_hi = (unsigned short*)alloc((size_t)MP_ * 128 * 2);
  unsigned short* sp   = (unsigned short*)alloc((size_t)MP_ * 128 * 2);
  unsigned short* lnB  = (unsigned short*)alloc((size_t)MP_ * 128 * 2);
  unsigned short* hid  = (unsigned short*)alloc((size_t)MP_ * 512 * 2);
  unsigned short* wqkv_hi = (unsigned short*)alloc((size_t)L_ * 384 * 128 * 2);
  unsigned short* wo_hi   = (unsigned short*)alloc((size_t)L_ * 128 * 128 * 2);
  unsigned short* w1_hi   = (unsigned short*)alloc((size_t)L_ * 512 * 128 * 2);
  unsigned short* w2_hi   = (unsigned short*)alloc((size_t)L_ * 128 * 512 * 2);
  unsigned short* we_hi   = (unsigned short*)alloc((size_t)128 * 64 * 2);
  unsigned short* we_lo   = (unsigned short*)alloc((size_t)128 * 64 * 2);
  float* qkvb = (float*)alloc((size_t)L_ * 384 * 4);
  float* cpart = (float*)alloc((size_t)256 * 128 * 4);
  float* cls_ws = (float*)alloc((size_t)CLS_TOT * 4);
  int* deg  = (int*)alloc((size_t)N_ * 4);
  int* cur  = (int*)alloc((size_t)N_ * 4);
  int* offs = (int*)alloc(((size_t)N_ + 1) * 4);
  int* csrc = (int*)alloc((size_t)E_ * 4);
  unsigned short* nf_hi = hid;
  unsigned short* nf_lo = hid + (size_t)MP_ * 64;

  const int* esrc = ei;
  const int* edst = ei + E_;

  prep_k<<<2048, 256, 0, stream>>>(
      qw, kw, vw, ow, mw1, mw2, emb_w, qb, kb, vb, node_features,
      cw1, cw2, clsw, cb1, cb2, clsb, clnw, clnb,
      wqkv_hi, wo_hi, w1_hi, w2_hi,
      we_hi, we_lo, qkvb, nf_hi, nf_lo, deg, cur, cls_ws);

  deg_k<<<(E_ + 255) / 256, 256, 0, stream>>>(edst, deg, E_);
  scan_k<<<1, 1024, 0, stream>>>(deg, offs, N_);
  fill_k<<<(E_ + 255) / 256, 256, 0, stream>>>(esrc, edst, offs, cur, csrc, E_);

  const dim3 g_embed(8 * 40 * 2);
  const dim3 g_qkv(8 * 40 * 6);
  const dim3 g_up(8 * 40 * 8);
  const dim3 g_down(8 * 40 * 2);   // RW=2: 64-row blocks

  // embed: h = nf @ emb_w + emb_b (fp32 + single bf16 plane); full precision
  mgemm3_k<64, 128, 0, true, 2, false, true, 2, true><<<g_embed, 128, 0, stream>>>(
      nf_hi, nf_lo, we_hi, we_lo, emb_b, nullptr, h, nullptr, h_hi, nullptr, N_);

  for (int i = 0; i < L_; ++i) {
    const unsigned short* wq_h = wqkv_hi + (size_t)i * 384 * 128;

    // fused QKV from single-plane h_hi, single-plane weights (1 MFMA/tile)
    mgemm3_k<128, 384, 0, false, 0, true, false, 2, false><<<g_qkv, 128, 0, stream>>>(
        h_hi, nullptr, wq_h, nullptr, qkvb + (size_t)i * 384, nullptr,
        nullptr, nullptr, kvbf, qbf, N_);

    agg_k<<<5000, 256, 0, stream>>>(qbf, kvbf, offs, csrc, sp, N_);

    // O-proj + residual + LN: 1-wave blocks, grid 1250
    ogemm_ln_k<<<dim3((N_ + 15) / 16), 64, 0, stream>>>(
        sp, wo_hi + (size_t)i * 128 * 128,
        ob + (size_t)i * 128, h, lnw + (size_t)i * 128, lnb + (size_t)i * 128,
        tmp, lnB, N_);

    // MLP up, single-plane weights (1 MFMA/tile)
    mgemm3_k<128, 512, 1, false, 2, false, false, 2, false><<<g_up, 128, 0, stream>>>(
        lnB, nullptr, w1_hi + (size_t)i * 512 * 128, nullptr,
        mb1 + (size_t)i * 512, nullptr, nullptr, nullptr, hid, nullptr, N_);

    // MLP down + residual: RW=2 (64-row blocks), single-plane weights
    if (i == L_ - 1) {
      mgemm3_k<512, 128, 2, true, 0, false, false, 2, false><<<g_down, 128, 0, stream>>>(
          hid, nullptr, w2_hi + (size_t)i * 128 * 512, nullptr,
          mb2 + (size_t)i * 128, tmp, h, out_h, nullptr, nullptr, N_);
    } else {
      mgemm3_k<512, 128, 2, true, 2, false, false, 2, false><<<g_down, 128, 0, stream>>>(
          hid, nullptr, w2_hi + (size_t)i * 128 * 512, nullptr,
          mb2 + (size_t)i * 128, tmp, h, nullptr, h_hi, nullptr, N_);
    }
  }

  colsum1_k<<<256, 256, 0, stream>>>(h, cpart, N_);
  classifier_k<<<1, 1024, 0, stream>>>(cpart, 256, cls_ws, out, out_g, 1.0f / (float)N_);
}

// Round 20
// 522.004 us; speedup vs baseline: 1.0387x; 1.0387x over previous
//
#include <hip/hip_runtime.h>
#include <hip/hip_bf16.h>
#include <cstdint>
#include <cstddef>

constexpr int N_  = 20000;
constexpr int E_  = 320000;
constexpr int DIM_ = 128;
constexpr int L_  = 4;
constexpr int MP_ = 20032;   // M padded

typedef short bf16x8 __attribute__((ext_vector_type(8)));
typedef float f32x4  __attribute__((ext_vector_type(4)));

__device__ __forceinline__ float gelu_f(float x) {
  float x3 = x * x * x;
  float z = 0.7978845608028654f * (x + 0.044715f * x3);
  float t = 1.f - 2.f / (__expf(2.f * z) + 1.f);   // tanh via fast exp
  return 0.5f * x * (1.0f + t);
}

__device__ __forceinline__ unsigned short f2bf(float x) {  // RNE
  unsigned u = __float_as_uint(x);
  u += 0x7fff + ((u >> 16) & 1);
  return (unsigned short)(u >> 16);
}
__device__ __forceinline__ float bf2f(unsigned short s) {
  return __uint_as_float((unsigned)s << 16);
}
__device__ __forceinline__ void splitf(float x, unsigned short& h, unsigned short& l) {
  h = f2bf(x);
  l = f2bf(x - bf2f(h));
}

// cls_ws layout offsets (floats)
constexpr int CW1_OFF  = 0;
constexpr int CW2_OFF  = 32768;
constexpr int CLSW_OFF = 65536;
constexpr int CB1_OFF  = 66816;
constexpr int CB2_OFF  = 67072;
constexpr int CLSB_OFF = 67200;
constexpr int CLNW_OFF = 67216;
constexpr int CLNB_OFF = 67344;
constexpr int CLS_TOT  = 67472;

// ---------------------------------------------------------------------------
// MFMA GEMM v5: fragment-major LDS staging, register-prefetched B staging.
// BSPLIT: B weights have a lo-plane (2 MFMAs/tile) or single bf16 (1 MFMA).
// ASPLIT: A has a lo-plane. RW = row-frags/wave. WB: 0 none,1 hi/lo,2 bf16.
// EPI: 0 none, 1 gelu, 2 +res. QPACK: q bf16 pre-scaled (Clo) + kv (Chi).
// ---------------------------------------------------------------------------
template <int K, int NC, int EPI, bool WF32, int WB, bool QPACK, bool ASPLIT,
          int RW, bool BSPLIT>
__global__ __launch_bounds__(128, 4) void mgemm3_k(
    const unsigned short* __restrict__ Ahi, const unsigned short* __restrict__ Alo,
    const unsigned short* __restrict__ Bthi, const unsigned short* __restrict__ Btlo,
    const float* __restrict__ bias, const float* __restrict__ res,
    float* __restrict__ Cf, float* __restrict__ Cf2,
    unsigned short* __restrict__ Chi, unsigned short* __restrict__ Clo,
    int M)
{
  constexpr int NCY = NC / 64;
  constexpr int BR  = RW * 32;
  constexpr int RPB = (RW == 2) ? 40 : 79;
  __shared__ unsigned short BsH[8 * 512];
  __shared__ unsigned short BsL[BSPLIT ? 8 * 512 : 8];

  const int bid = blockIdx.x;
  const int g   = bid & 7;
  const int s   = bid >> 3;
  const int lr  = s / NCY;
  const int cc  = s - lr * NCY;
  const int rb  = g * RPB + lr;
  if (rb * BR >= M) return;

  const int tid  = threadIdx.x;
  const int wave = tid >> 6;
  const int lane = tid & 63;
  const int l15  = lane & 15;
  const int kq8  = (lane >> 4) * 8;
  const int r0   = rb * BR + wave * (RW * 16);
  const int c0   = cc * 64;

  const int brow  = tid & 63;
  const int bhalf = tid >> 6;
  const int sbase = ((brow >> 4) * 2 + bhalf) * 512 + (brow & 15) * 8;
  const unsigned short* bh_src = Bthi + (size_t)(c0 + brow) * K + bhalf * 32;
  const unsigned short* bl_src = BSPLIT ? (Btlo + (size_t)(c0 + brow) * K + bhalf * 32)
                                        : bh_src;

  f32x4 acc[RW][4];
#pragma unroll
  for (int rw = 0; rw < RW; ++rw)
#pragma unroll
    for (int ct = 0; ct < 4; ++ct) acc[rw][ct] = (f32x4){0.f, 0.f, 0.f, 0.f};

  const unsigned short* arh[2];
  const unsigned short* arl[2];
  arh[0] = Ahi + (size_t)(r0 + l15) * K + kq8;
  arh[1] = (RW == 2) ? (Ahi + (size_t)(r0 + 16 + l15) * K + kq8) : arh[0];
  arl[0] = ASPLIT ? (Alo + (size_t)(r0 + l15) * K + kq8) : arh[0];
  arl[1] = (ASPLIT && RW == 2) ? (Alo + (size_t)(r0 + 16 + l15) * K + kq8) : arl[0];

  constexpr int NCH = K / 64;
  bf16x8 rh0[4], rl0[4], rh1[4], rl1[4];
#pragma unroll
  for (int st = 0; st < 4; ++st) {
    rh0[st] = *(const bf16x8*)(bh_src + st * 8);
    if constexpr (BSPLIT) rl0[st] = *(const bf16x8*)(bl_src + st * 8);
  }

#pragma unroll
  for (int c = 0; c < NCH; ++c) {
    const int ck = c * 64;
    if (c > 0) __syncthreads();
#pragma unroll
    for (int st = 0; st < 4; ++st) {
      if (c & 1) {
        *(bf16x8*)&BsH[sbase + st * 128] = rh1[st];
        if constexpr (BSPLIT) *(bf16x8*)&BsL[sbase + st * 128] = rl1[st];
      } else {
        *(bf16x8*)&BsH[sbase + st * 128] = rh0[st];
        if constexpr (BSPLIT) *(bf16x8*)&BsL[sbase + st * 128] = rl0[st];
      }
    }
    if (c + 1 < NCH) {
      const int ck2 = (c + 1) * 64;
#pragma unroll
      for (int st = 0; st < 4; ++st) {
        if (c & 1) {
          rh0[st] = *(const bf16x8*)(bh_src + ck2 + st * 8);
          if constexpr (BSPLIT) rl0[st] = *(const bf16x8*)(bl_src + ck2 + st * 8);
        } else {
          rh1[st] = *(const bf16x8*)(bh_src + ck2 + st * 8);
          if constexpr (BSPLIT) rl1[st] = *(const bf16x8*)(bl_src + ck2 + st * 8);
        }
      }
    }
    __syncthreads();
#pragma unroll
    for (int k0 = 0; k0 < 2; ++k0) {
      bf16x8 ah[RW], al[RW];
#pragma unroll
      for (int rw = 0; rw < RW; ++rw) {
        ah[rw] = *(const bf16x8*)(arh[rw] + ck + k0 * 32);
        if (ASPLIT) al[rw] = *(const bf16x8*)(arl[rw] + ck + k0 * 32);
      }
#pragma unroll
      for (int ct = 0; ct < 4; ++ct) {
        const int fb = (ct * 2 + k0) * 512 + lane * 8;
        bf16x8 bh = *(const bf16x8*)&BsH[fb];
#pragma unroll
        for (int rw = 0; rw < RW; ++rw) {
          acc[rw][ct] = __builtin_amdgcn_mfma_f32_16x16x32_bf16(ah[rw], bh, acc[rw][ct], 0, 0, 0);
          if constexpr (BSPLIT) {
            bf16x8 bl = *(const bf16x8*)&BsL[fb];
            acc[rw][ct] = __builtin_amdgcn_mfma_f32_16x16x32_bf16(ah[rw], bl, acc[rw][ct], 0, 0, 0);
          }
          if (ASPLIT)
            acc[rw][ct] = __builtin_amdgcn_mfma_f32_16x16x32_bf16(al[rw], bh, acc[rw][ct], 0, 0, 0);
        }
      }
    }
  }

  const int ccol  = lane & 15;
  const int crow0 = (lane >> 4) * 4;
#pragma unroll
  for (int rw = 0; rw < RW; ++rw) {
#pragma unroll
    for (int ct = 0; ct < 4; ++ct) {
      int gc = c0 + ct * 16 + ccol;
      float bb = bias[gc];
#pragma unroll
      for (int r = 0; r < 4; ++r) {
        int gr = r0 + rw * 16 + crow0 + r;
        if (gr >= M) continue;
        float o = acc[rw][ct][r] + bb;
        if (EPI == 1) o = gelu_f(o);
        if (EPI == 2) o += res[(size_t)gr * NC + gc];
        if (QPACK) {
          if (c0 < 128) Clo[(size_t)gr * 128 + gc] = f2bf(o * 0.17677669529663687f);
          else          Chi[(size_t)gr * 256 + gc - 128] = f2bf(o);
        } else {
          if (WF32) {
            Cf[(size_t)gr * NC + gc] = o;
            if (Cf2) Cf2[(size_t)gr * NC + gc] = o;
          }
          if (WB == 1) {
            unsigned short hh, ll;
            splitf(o, hh, ll);
            Chi[(size_t)gr * NC + gc] = hh;
            Clo[(size_t)gr * NC + gc] = ll;
          }
          if (WB == 2) Chi[(size_t)gr * NC + gc] = f2bf(o);
        }
      }
    }
  }
}

// ---------------------------------------------------------------------------
// Fused O-projection + residual + LayerNorm. B single bf16 plane (1 MFMA).
// 2-wave blocks, 32 rows each (R18 configuration).
// ---------------------------------------------------------------------------
__global__ __launch_bounds__(128, 4) void ogemm_ln_k(
    const unsigned short* __restrict__ A,
    const unsigned short* __restrict__ Bt,
    const float* __restrict__ bias, const float* __restrict__ resid,
    const float* __restrict__ lnw, const float* __restrict__ lnb,
    float* __restrict__ lnF, unsigned short* __restrict__ lnB, int M)
{
  const int wave = threadIdx.x >> 6;
  const int lane = threadIdx.x & 63;
  const int l15  = lane & 15;
  const int kq8  = (lane >> 4) * 8;
  const int r0   = blockIdx.x * 32 + wave * 16;

  f32x4 acc[8];
#pragma unroll
  for (int ct = 0; ct < 8; ++ct) acc[ct] = (f32x4){0.f, 0.f, 0.f, 0.f};

  const unsigned short* ar  = A + (size_t)(r0 + l15) * 128 + kq8;
  const unsigned short* bth = Bt + (size_t)l15 * 128 + kq8;

#pragma unroll
  for (int k0 = 0; k0 < 128; k0 += 32) {
    bf16x8 ah = *(const bf16x8*)(ar + k0);
#pragma unroll
    for (int ct = 0; ct < 8; ++ct) {
      bf16x8 bh = *(const bf16x8*)(bth + ct * 16 * 128 + k0);
      acc[ct] = __builtin_amdgcn_mfma_f32_16x16x32_bf16(ah, bh, acc[ct], 0, 0, 0);
    }
  }

  const int ccol  = lane & 15;
  const int crow0 = (lane >> 4) * 4;

#pragma unroll
  for (int ct = 0; ct < 8; ++ct) {
    int gc = ct * 16 + ccol;
    float bb = bias[gc];
#pragma unroll
    for (int r = 0; r < 4; ++r) {
      int gr = r0 + crow0 + r;
      acc[ct][r] += bb + resid[(size_t)gr * 128 + gc];
    }
  }

  float mu[4];
#pragma unroll
  for (int r = 0; r < 4; ++r) {
    float s = 0.f;
#pragma unroll
    for (int ct = 0; ct < 8; ++ct) s += acc[ct][r];
    s += __shfl_xor(s, 1); s += __shfl_xor(s, 2);
    s += __shfl_xor(s, 4); s += __shfl_xor(s, 8);
    mu[r] = s * (1.f / 128.f);
  }
  float rstd[4];
#pragma unroll
  for (int r = 0; r < 4; ++r) {
    float s = 0.f;
#pragma unroll
    for (int ct = 0; ct < 8; ++ct) { float d = acc[ct][r] - mu[r]; s += d * d; }
    s += __shfl_xor(s, 1); s += __shfl_xor(s, 2);
    s += __shfl_xor(s, 4); s += __shfl_xor(s, 8);
    rstd[r] = rsqrtf(s * (1.f / 128.f) + 1e-5f);
  }

#pragma unroll
  for (int ct = 0; ct < 8; ++ct) {
    int gc = ct * 16 + ccol;
    float ww = lnw[gc], bb = lnb[gc];
#pragma unroll
    for (int r = 0; r < 4; ++r) {
      int gr = r0 + crow0 + r;
      if (gr >= M) continue;
      float o = (acc[ct][r] - mu[r]) * rstd[r] * ww + bb;
      lnF[(size_t)gr * 128 + gc] = o;
      lnB[(size_t)gr * 128 + gc] = f2bf(o);
    }
  }
}

// ---------------------------------------------------------------------------
// prep_k: weight prep (all layer weights single bf16; embed keeps hi/lo) +
// classifier warm-copy + zeroing.
// ---------------------------------------------------------------------------
__global__ __launch_bounds__(256) void prep_k(
    const float* __restrict__ qw, const float* __restrict__ kw,
    const float* __restrict__ vw, const float* __restrict__ ow,
    const float* __restrict__ mw1, const float* __restrict__ mw2,
    const float* __restrict__ emb_w,
    const float* __restrict__ qb, const float* __restrict__ kb,
    const float* __restrict__ vb,
    const float* __restrict__ nf,
    const float* __restrict__ cw1, const float* __restrict__ cw2,
    const float* __restrict__ clsw, const float* __restrict__ cb1,
    const float* __restrict__ cb2, const float* __restrict__ clsb,
    const float* __restrict__ clnw, const float* __restrict__ clnb,
    unsigned short* __restrict__ wqkv_hi,
    unsigned short* __restrict__ wo_hi,
    unsigned short* __restrict__ w1_hi,
    unsigned short* __restrict__ w2_hi,
    unsigned short* __restrict__ we_hi, unsigned short* __restrict__ we_lo,
    float* __restrict__ qkvb,
    unsigned short* __restrict__ nf_hi, unsigned short* __restrict__ nf_lo,
    int* __restrict__ deg, int* __restrict__ cur,
    float* __restrict__ cls_ws)
{
  constexpr int T_qkv = 3 * L_ * 16384;
  constexpr int T_o   = T_qkv + L_ * 16384;
  constexpr int T_w1  = T_o + L_ * 65536;
  constexpr int T_w2  = T_w1 + L_ * 65536;
  constexpr int T_we  = T_w2 + 8192;
  constexpr int T_b   = T_we + L_ * 384;
  constexpr int T_nf  = T_b + N_ * 64;
  constexpr int T_z   = T_nf + 2 * N_;
  constexpr int T_cls = T_z + CLS_TOT;

  unsigned short hh, ll;
  for (int i = blockIdx.x * 256 + threadIdx.x; i < T_cls; i += gridDim.x * 256) {
    if (i < T_qkv) {
      int which = i / (L_ * 16384);
      int r = i - which * (L_ * 16384);
      int l = r >> 14, rr = r & 16383;
      int k = rr >> 7, c = rr & 127;
      const float* src = (which == 0) ? qw : (which == 1) ? kw : vw;
      size_t op = (size_t)l * 49152 + (size_t)(which * 128 + c) * 128 + k;
      wqkv_hi[op] = f2bf(src[r]);
    } else if (i < T_o) {
      int r = i - T_qkv;
      int l = r >> 14, rr = r & 16383;
      int k = rr >> 7, c = rr & 127;
      size_t op = (size_t)l * 16384 + (size_t)c * 128 + k;
      wo_hi[op] = f2bf(ow[r]);
    } else if (i < T_w1) {
      int r = i - T_o;
      int l = r >> 16, rr = r & 65535;
      int k = rr >> 9, c = rr & 511;
      size_t op = (size_t)l * 65536 + (size_t)c * 128 + k;
      w1_hi[op] = f2bf(mw1[r]);
    } else if (i < T_w2) {
      int r = i - T_w1;
      int l = r >> 16, rr = r & 65535;
      int k = rr >> 7, c = rr & 127;
      size_t op = (size_t)l * 65536 + (size_t)c * 512 + k;
      w2_hi[op] = f2bf(mw2[r]);
    } else if (i < T_we) {
      int r = i - T_w2;
      int k = r >> 7, c = r & 127;
      splitf(emb_w[r], hh, ll);
      size_t op = (size_t)c * 64 + k;
      we_hi[op] = hh; we_lo[op] = ll;
    } else if (i < T_b) {
      int r = i - T_we;
      int l = r / 384, c = r - l * 384;
      float x = (c < 128) ? qb[l * 128 + c]
              : (c < 256) ? kb[l * 128 + c - 128]
                          : vb[l * 128 + c - 256];
      qkvb[r] = x;
    } else if (i < T_nf) {
      int r = i - T_b;
      splitf(nf[r], hh, ll);
      nf_hi[r] = hh; nf_lo[r] = ll;
    } else if (i < T_z) {
      int r = i - T_nf;
      if (r < N_) deg[r] = 0;
      else cur[r - N_] = 0;
    } else {
      int j = i - T_z;
      float v;
      if (j < CW2_OFF)       v = cw1[j];
      else if (j < CLSW_OFF) v = cw2[j - CW2_OFF];
      else if (j < CB1_OFF)  v = clsw[j - CLSW_OFF];
      else if (j < CB2_OFF)  v = cb1[j - CB1_OFF];
      else if (j < CLSB_OFF) v = cb2[j - CB2_OFF];
      else if (j < CLNW_OFF) v = (j - CLSB_OFF < 10) ? clsb[j - CLSB_OFF] : 0.f;
      else if (j < CLNB_OFF) v = clnw[j - CLNW_OFF];
      else                   v = clnb[j - CLNB_OFF];
      cls_ws[j] = v;
    }
  }
}

// ---------------------------------------------------------------------------
// CSR build
// ---------------------------------------------------------------------------
__global__ __launch_bounds__(256) void deg_k(const int* __restrict__ dst, int* __restrict__ deg, int E) {
  int e = blockIdx.x * blockDim.x + threadIdx.x;
  if (e < E) atomicAdd(&deg[dst[e]], 1);
}

__global__ __launch_bounds__(1024) void scan_k(const int* __restrict__ deg, int* __restrict__ offs, int n) {
  __shared__ int part[1024];
  int tid = threadIdx.x;
  const int chunk = (n + 1023) / 1024;
  int base = tid * chunk;
  int s = 0;
  for (int j = 0; j < chunk; ++j) { int idx = base + j; if (idx < n) s += deg[idx]; }
  part[tid] = s;
  __syncthreads();
  int own = s;
  for (int off = 1; off < 1024; off <<= 1) {
    int t = (tid >= off) ? part[tid - off] : 0;
    __syncthreads();
    part[tid] += t;
    __syncthreads();
  }
  int run = part[tid] - own;
  for (int j = 0; j < chunk; ++j) {
    int idx = base + j;
    if (idx <= n) offs[idx] = run;
    if (idx < n) run += deg[idx];
  }
}

__global__ __launch_bounds__(256) void fill_k(
    const int* __restrict__ src, const int* __restrict__ dst,
    const int* __restrict__ offs, int* __restrict__ cur,
    int* __restrict__ csrc, int E)
{
  int e = blockIdx.x * blockDim.x + threadIdx.x;
  if (e < E) {
    int d = dst[e];
    int p = atomicAdd(&cur[d], 1);
    csrc[offs[d] + p] = src[e];
  }
}

// ---------------------------------------------------------------------------
// Fused attention v3: wave per node, 16-edge chunks x 4 heads, early V-issue.
// ---------------------------------------------------------------------------
__global__ __launch_bounds__(256) void agg_k(
    const unsigned short* __restrict__ qbf, const unsigned short* __restrict__ kvbf,
    const int* __restrict__ offs, const int* __restrict__ csrc,
    unsigned short* __restrict__ agg, int M)
{
  int nb = blockIdx.x;
  int bid = (nb & 7) * 625 + (nb >> 3);
  int n = bid * 4 + (int)(threadIdx.x >> 6);
  int lane = threadIdx.x & 63;
  if (n >= M) return;
  const int e0 = offs[n], e1 = offs[n + 1];
  const int col2 = lane * 2;
  if (e0 == e1) {
    *(unsigned*)&agg[(size_t)n * 128 + col2] = 0;
    return;
  }
  const int eloc = lane & 15;
  const int hgrp = lane & 48;

  const unsigned short* qr = qbf + (size_t)n * 128 + (lane >> 4) * 32;
  float qf[32];
#pragma unroll
  for (int i = 0; i < 4; ++i) {
    uint4 t = *(const uint4*)(qr + i * 8);
    unsigned u0 = t.x, u1 = t.y, u2 = t.z, u3 = t.w;
    qf[i * 8 + 0] = __uint_as_float(u0 << 16);
    qf[i * 8 + 1] = __uint_as_float(u0 & 0xffff0000u);
    qf[i * 8 + 2] = __uint_as_float(u1 << 16);
    qf[i * 8 + 3] = __uint_as_float(u1 & 0xffff0000u);
    qf[i * 8 + 4] = __uint_as_float(u2 << 16);
    qf[i * 8 + 5] = __uint_as_float(u2 & 0xffff0000u);
    qf[i * 8 + 6] = __uint_as_float(u3 << 16);
    qf[i * 8 + 7] = __uint_as_float(u3 & 0xffff0000u);
  }

  float denp = 0.f, acc0 = 0.f, acc1 = 0.f;
  for (int c = e0; c < e1; c += 16) {
    int e = c + eloc;
    bool val = e < e1;
    int sv = csrc[val ? e : e1 - 1];

    unsigned vv[16];
#pragma unroll
    for (int i = 0; i < 16; ++i) {
      int sb = __shfl(sv, hgrp + i);
      vv[i] = *(const unsigned*)(kvbf + (size_t)sb * 256 + 128 + col2);
    }

    const unsigned short* kr = kvbf + (size_t)sv * 256 + (lane >> 4) * 32;
    float dot = 0.f;
#pragma unroll
    for (int i = 0; i < 4; ++i) {
      uint4 t = *(const uint4*)(kr + i * 8);
      unsigned u0 = t.x, u1 = t.y, u2 = t.z, u3 = t.w;
      dot = fmaf(qf[i * 8 + 0], __uint_as_float(u0 << 16), dot);
      dot = fmaf(qf[i * 8 + 1], __uint_as_float(u0 & 0xffff0000u), dot);
      dot = fmaf(qf[i * 8 + 2], __uint_as_float(u1 << 16), dot);
      dot = fmaf(qf[i * 8 + 3], __uint_as_float(u1 & 0xffff0000u), dot);
      dot = fmaf(qf[i * 8 + 4], __uint_as_float(u2 << 16), dot);
      dot = fmaf(qf[i * 8 + 5], __uint_as_float(u2 & 0xffff0000u), dot);
      dot = fmaf(qf[i * 8 + 6], __uint_as_float(u3 << 16), dot);
      dot = fmaf(qf[i * 8 + 7], __uint_as_float(u3 & 0xffff0000u), dot);
    }
    float w = val ? __expf(dot) : 0.f;
    denp += w;

#pragma unroll
    for (int i = 0; i < 16; ++i) {
      float wi = __shfl(w, hgrp + i);
      acc0 = fmaf(wi, __uint_as_float(vv[i] << 16), acc0);
      acc1 = fmaf(wi, __uint_as_float(vv[i] & 0xffff0000u), acc1);
    }
  }
  float den = denp;
  den += __shfl_xor(den, 1);
  den += __shfl_xor(den, 2);
  den += __shfl_xor(den, 4);
  den += __shfl_xor(den, 8);
  float r = 1.f / den;
  unsigned o0 = f2bf(acc0 * r);
  unsigned o1 = f2bf(acc1 * r);
  *(unsigned*)&agg[(size_t)n * 128 + col2] = o0 | (o1 << 16);
}

// ---------------------------------------------------------------------------
// Column sum stage 1
// ---------------------------------------------------------------------------
__global__ __launch_bounds__(256) void colsum1_k(
    const float* __restrict__ h, float* __restrict__ partial, int M)
{
  __shared__ float sd[8][128];
  int tid = threadIdx.x;
  int cq = (tid & 31) * 4;
  int rg = tid >> 5;
  float4 s = make_float4(0.f, 0.f, 0.f, 0.f);
  for (int r = blockIdx.x * 8 + rg; r < M; r += gridDim.x * 8) {
    float4 v = *(const float4*)(h + (size_t)r * 128 + cq);
    s.x += v.x; s.y += v.y; s.z += v.z; s.w += v.w;
  }
  *(float4*)&sd[rg][cq] = s;
  __syncthreads();
  if (tid < 32) {
    int c4 = tid * 4;
    float4 a = *(float4*)&sd[0][c4];
#pragma unroll
    for (int g2 = 1; g2 < 8; ++g2) {
      float4 b = *(float4*)&sd[g2][c4];
      a.x += b.x; a.y += b.y; a.z += b.z; a.w += b.w;
    }
    *(float4*)&partial[(size_t)blockIdx.x * 128 + c4] = a;
  }
}

// ---------------------------------------------------------------------------
// classifier: 1024 threads, LDS-split dots, L3-warm cls_ws copy.
// ---------------------------------------------------------------------------
__global__ __launch_bounds__(1024) void classifier_k(
    const float* __restrict__ partial, int P,
    const float* __restrict__ cls,
    float* __restrict__ out_logits, float* __restrict__ out_g, float invN)
{
  __shared__ float scratch[1024];
  __shared__ float z[128], h1b[256], z2[128];
  const int tid = threadIdx.x;

  {
    int col = tid & 127, ch = tid >> 7;
    float s = 0.f;
    for (int i = ch; i < P; i += 8) s += partial[(size_t)i * 128 + col];
    scratch[tid] = s;
  }
  __syncthreads();
  if (tid < 128) {
    float s = 0.f;
#pragma unroll
    for (int j = 0; j < 8; ++j) s += scratch[tid + j * 128];
    float gg = s * invN;
    out_g[tid] = gg;
    z[tid] = gg;
  }
  __syncthreads();

  if (tid < 64) {
    float a = z[tid], b2 = z[tid + 64];
    float s = a + b2;
#pragma unroll
    for (int d = 1; d < 64; d <<= 1) s += __shfl_xor(s, d);
    float mean = s * (1.f / 128.f);
    float ea = a - mean, eb = b2 - mean;
    float sq = ea * ea + eb * eb;
#pragma unroll
    for (int d = 1; d < 64; d <<= 1) sq += __shfl_xor(sq, d);
    float rstd = rsqrtf(sq * (1.f / 128.f) + 1e-5f);
    z[tid]      = ea * rstd * cls[CLNW_OFF + tid] + cls[CLNB_OFF + tid];
    z[tid + 64] = eb * rstd * cls[CLNW_OFF + tid + 64] + cls[CLNB_OFF + tid + 64];
  }
  __syncthreads();

  {
    int o = tid & 255, ch = tid >> 8;
    float s = 0.f;
#pragma unroll
    for (int f = 0; f < 32; ++f)
      s = fmaf(z[ch * 32 + f], cls[CW1_OFF + (ch * 32 + f) * 256 + o], s);
    scratch[tid] = s;
  }
  __syncthreads();
  if (tid < 256) {
    float s = cls[CB1_OFF + tid];
#pragma unroll
    for (int j = 0; j < 4; ++j) s += scratch[tid + j * 256];
    h1b[tid] = gelu_f(s);
  }
  __syncthreads();

  {
    int o = tid & 127, ch = tid >> 7;
    float s = 0.f;
#pragma unroll
    for (int f = 0; f < 32; ++f)
      s = fmaf(h1b[ch * 32 + f], cls[CW2_OFF + (ch * 32 + f) * 128 + o], s);
    scratch[tid] = s;
  }
  __syncthreads();
  if (tid < 128) {
    float s = cls[CB2_OFF + tid];
#pragma unroll
    for (int j = 0; j < 8; ++j) s += scratch[tid + j * 128];
    z2[tid] = s;
  }
  __syncthreads();

  {
    int wv = tid >> 6, ln = tid & 63;
    if (wv < 10) {
      float s = z2[ln] * cls[CLSW_OFF + ln * 10 + wv]
              + z2[ln + 64] * cls[CLSW_OFF + (ln + 64) * 10 + wv];
#pragma unroll
      for (int d = 1; d < 64; d <<= 1) s += __shfl_xor(s, d);
      if (ln == 0) out_logits[wv] = s + cls[CLSB_OFF + wv];
    }
  }
}

// ---------------------------------------------------------------------------
extern "C" void kernel_launch(void* const* d_in, const int* in_sizes, int n_in,
                              void* d_out, int out_size, void* d_ws, size_t ws_size,
                              hipStream_t stream) {
  const float* node_features = (const float*)d_in[0];
  const int*   ei            = (const int*)d_in[1];
  const float* emb_w = (const float*)d_in[3];
  const float* emb_b = (const float*)d_in[4];
  const float* qw  = (const float*)d_in[7];  const float* qb  = (const float*)d_in[8];
  const float* kw  = (const float*)d_in[9];  const float* kb  = (const float*)d_in[10];
  const float* vw  = (const float*)d_in[11]; const float* vb  = (const float*)d_in[12];
  const float* ow  = (const float*)d_in[13]; const float* ob  = (const float*)d_in[14];
  const float* lnw = (const float*)d_in[15]; const float* lnb = (const float*)d_in[16];
  const float* mw1 = (const float*)d_in[17]; const float* mb1 = (const float*)d_in[18];
  const float* mw2 = (const float*)d_in[19]; const float* mb2 = (const float*)d_in[20];
  const float* clnw = (const float*)d_in[21]; const float* clnb = (const float*)d_in[22];
  const float* cw1 = (const float*)d_in[23]; const float* cb1 = (const float*)d_in[24];
  const float* cw2 = (const float*)d_in[25]; const float* cb2 = (const float*)d_in[26];
  const float* clsw = (const float*)d_in[27]; const float* clsb = (const float*)d_in[28];

  float* out = (float*)d_out;
  float* out_h = out + 10;
  float* out_g = out + 10 + (size_t)N_ * DIM_;

  char* p = (char*)d_ws;
  auto alloc = [&](size_t bytes) { char* r = p; p += (bytes + 255) & ~(size_t)255; return r; };

  float* h    = (float*)alloc((size_t)MP_ * 128 * 4);
  float* tmp  = (float*)alloc((size_t)MP_ * 128 * 4);
  unsigned short* qbf  = (unsigned short*)alloc((size_t)MP_ * 128 * 2);
  unsigned short* kvbf = (unsigned short*)alloc((size_t)MP_ * 256 * 2);
  unsigned short* h_hi = (unsigned short*)alloc((size_t)MP_ * 128 * 2);
  unsigned short* sp   = (unsigned short*)alloc((size_t)MP_ * 128 * 2);
  unsigned short* lnB  = (unsigned short*)alloc((size_t)MP_ * 128 * 2);
  unsigned short* hid  = (unsigned short*)alloc((size_t)MP_ * 512 * 2);
  unsigned short* wqkv_hi = (unsigned short*)alloc((size_t)L_ * 384 * 128 * 2);
  unsigned short* wo_hi   = (unsigned short*)alloc((size_t)L_ * 128 * 128 * 2);
  unsigned short* w1_hi   = (unsigned short*)alloc((size_t)L_ * 512 * 128 * 2);
  unsigned short* w2_hi   = (unsigned short*)alloc((size_t)L_ * 128 * 512 * 2);
  unsigned short* we_hi   = (unsigned short*)alloc((size_t)128 * 64 * 2);
  unsigned short* we_lo   = (unsigned short*)alloc((size_t)128 * 64 * 2);
  float* qkvb = (float*)alloc((size_t)L_ * 384 * 4);
  float* cpart = (float*)alloc((size_t)256 * 128 * 4);
  float* cls_ws = (float*)alloc((size_t)CLS_TOT * 4);
  int* deg  = (int*)alloc((size_t)N_ * 4);
  int* cur  = (int*)alloc((size_t)N_ * 4);
  int* offs = (int*)alloc(((size_t)N_ + 1) * 4);
  int* csrc = (int*)alloc((size_t)E_ * 4);
  unsigned short* nf_hi = hid;
  unsigned short* nf_lo = hid + (size_t)MP_ * 64;

  const int* esrc = ei;
  const int* edst = ei + E_;

  prep_k<<<2048, 256, 0, stream>>>(
      qw, kw, vw, ow, mw1, mw2, emb_w, qb, kb, vb, node_features,
      cw1, cw2, clsw, cb1, cb2, clsb, clnw, clnb,
      wqkv_hi, wo_hi, w1_hi, w2_hi,
      we_hi, we_lo, qkvb, nf_hi, nf_lo, deg, cur, cls_ws);

  deg_k<<<(E_ + 255) / 256, 256, 0, stream>>>(edst, deg, E_);
  scan_k<<<1, 1024, 0, stream>>>(deg, offs, N_);
  fill_k<<<(E_ + 255) / 256, 256, 0, stream>>>(esrc, edst, offs, cur, csrc, E_);

  const dim3 g_embed(8 * 40 * 2);
  const dim3 g_qkv(8 * 40 * 6);
  const dim3 g_up(8 * 40 * 8);
  const dim3 g_down(8 * 79 * 2);   // RW=1: 32-row blocks (R18 config)

  // embed: h = nf @ emb_w + emb_b (fp32 + single bf16 plane); full precision
  mgemm3_k<64, 128, 0, true, 2, false, true, 2, true><<<g_embed, 128, 0, stream>>>(
      nf_hi, nf_lo, we_hi, we_lo, emb_b, nullptr, h, nullptr, h_hi, nullptr, N_);

  for (int i = 0; i < L_; ++i) {
    const unsigned short* wq_h = wqkv_hi + (size_t)i * 384 * 128;

    // fused QKV from single-plane h_hi, single-plane weights (1 MFMA/tile)
    mgemm3_k<128, 384, 0, false, 0, true, false, 2, false><<<g_qkv, 128, 0, stream>>>(
        h_hi, nullptr, wq_h, nullptr, qkvb + (size_t)i * 384, nullptr,
        nullptr, nullptr, kvbf, qbf, N_);

    agg_k<<<5000, 256, 0, stream>>>(qbf, kvbf, offs, csrc, sp, N_);

    // O-proj + residual + LN, 2-wave blocks (R18 config)
    ogemm_ln_k<<<dim3((N_ + 31) / 32), 128, 0, stream>>>(
        sp, wo_hi + (size_t)i * 128 * 128,
        ob + (size_t)i * 128, h, lnw + (size_t)i * 128, lnb + (size_t)i * 128,
        tmp, lnB, N_);

    // MLP up, single-plane weights (1 MFMA/tile)
    mgemm3_k<128, 512, 1, false, 2, false, false, 2, false><<<g_up, 128, 0, stream>>>(
        lnB, nullptr, w1_hi + (size_t)i * 512 * 128, nullptr,
        mb1 + (size_t)i * 512, nullptr, nullptr, nullptr, hid, nullptr, N_);

    // MLP down + residual: RW=1 (32-row blocks, grid 1264 — R18 config)
    if (i == L_ - 1) {
      mgemm3_k<512, 128, 2, true, 0, false, false, 1, false><<<g_down, 128, 0, stream>>>(
          hid, nullptr, w2_hi + (size_t)i * 128 * 512, nullptr,
          mb2 + (size_t)i * 128, tmp, h, out_h, nullptr, nullptr, N_);
    } else {
      mgemm3_k<512, 128, 2, true, 2, false, false, 1, false><<<g_down, 128, 0, stream>>>(
          hid, nullptr, w2_hi + (size_t)i * 128 * 512, nullptr,
          mb2 + (size_t)i * 128, tmp, h, nullptr, h_hi, nullptr, N_);
    }
  }

  colsum1_k<<<256, 256, 0, stream>>>(h, cpart, N_);
  classifier_k<<<1, 1024, 0, stream>>>(cpart, 256, cls_ws, out, out_g, 1.0f / (float)N_);
}